// Round 10
// baseline (9967.113 us; speedup 1.0000x reference)
//
#include <hip/hip_runtime.h>
#include <stdint.h>

#define BB 128
#define SS 2048
#define TT 128
#define NSEG 32
#define SEGK 64

#define TRP 129              // trans row stride in LDS (129 % 32 == 1)

typedef float f32x4 __attribute__((ext_vector_type(4)));

#define PIN(x) asm volatile("" : "+v"(x))

__device__ __forceinline__ f32x4 fmax4v(f32x4 a, f32x4 b) {
    f32x4 r;
    r.x = fmaxf(a.x, b.x); r.y = fmaxf(a.y, b.y);
    r.z = fmaxf(a.z, b.z); r.w = fmaxf(a.w, b.w);
    return r;
}

#define CLAMPROW(k) (((k) < L) ? (k) : (L - 1))

// ---- one viterbi column, fully within-lane (no cross-lane ops) ----
// pass1: chunk maxes of q = s + T (streamed, not kept); v = (max q) + e  (exact
// monotone identity, validated R2-R9). first chunk with (cm+e)==v always exists
// and always contains an element with (q+e)==v. rescan that chunk from LDS
// (bit-identical recompute) with descending first-index selects.
#define VCOL(OUTV, OUTI, TREG, ECOL, JCOL)                                    \
{                                                                             \
    const f32x4* sp_ = (const f32x4*)(stateLDS + cur_ * TT);                  \
    float cm_[16];                                                            \
    _Pragma("unroll")                                                         \
    for (int cc = 0; cc < 16; ++cc) {                                         \
        f32x4 qa_ = sp_[2 * cc] + TREG[2 * cc];                               \
        f32x4 qb_ = sp_[2 * cc + 1] + TREG[2 * cc + 1];                       \
        f32x4 m4_ = fmax4v(qa_, qb_);                                         \
        cm_[cc] = fmaxf(fmaxf(m4_.x, m4_.y), fmaxf(m4_.z, m4_.w));            \
    }                                                                         \
    float M_ = fmaxf(                                                         \
        fmaxf(fmaxf(fmaxf(cm_[0], cm_[1]), cm_[2]),                           \
              fmaxf(fmaxf(cm_[3], cm_[4]), fmaxf(cm_[5], cm_[6]))),           \
        fmaxf(fmaxf(fmaxf(cm_[7], cm_[8]), fmaxf(cm_[9], cm_[10])),           \
              fmaxf(fmaxf(cm_[11], fmaxf(cm_[12], cm_[13])),                  \
                    fmaxf(cm_[14], cm_[15]))));                               \
    const float v_ = M_ + (ECOL);                                             \
    int cwin_ = 15;                                                           \
    _Pragma("unroll")                                                         \
    for (int cc = 14; cc >= 0; --cc)                                          \
        cwin_ = ((cm_[cc] + (ECOL)) == v_) ? cc : cwin_;                      \
    const int kb_ = cwin_ * 8;                                                \
    const f32x4* sr_ = (const f32x4*)(stateLDS + cur_ * TT + kb_);            \
    f32x4 ra_ = sr_[0], rb_ = sr_[1];                                         \
    const float* tr_ = transLDS + (size_t)kb_ * TRP + (JCOL);                 \
    float q0_ = (ra_.x + tr_[0 * TRP]) + (ECOL);                              \
    float q1_ = (ra_.y + tr_[1 * TRP]) + (ECOL);                              \
    float q2_ = (ra_.z + tr_[2 * TRP]) + (ECOL);                              \
    float q3_ = (ra_.w + tr_[3 * TRP]) + (ECOL);                              \
    float q4_ = (rb_.x + tr_[4 * TRP]) + (ECOL);                              \
    float q5_ = (rb_.y + tr_[5 * TRP]) + (ECOL);                              \
    float q6_ = (rb_.z + tr_[6 * TRP]) + (ECOL);                              \
    float q7_ = (rb_.w + tr_[7 * TRP]) + (ECOL);                              \
    int idx_ = 0x7fffffff;                                                    \
    idx_ = (q7_ == v_) ? kb_ + 7 : idx_;                                      \
    idx_ = (q6_ == v_) ? kb_ + 6 : idx_;                                      \
    idx_ = (q5_ == v_) ? kb_ + 5 : idx_;                                      \
    idx_ = (q4_ == v_) ? kb_ + 4 : idx_;                                      \
    idx_ = (q3_ == v_) ? kb_ + 3 : idx_;                                      \
    idx_ = (q2_ == v_) ? kb_ + 2 : idx_;                                      \
    idx_ = (q1_ == v_) ? kb_ + 1 : idx_;                                      \
    idx_ = (q0_ == v_) ? kb_ + 0 : idx_;                                      \
    OUTV = v_; OUTI = idx_;                                                   \
}

// one 1-wave viterbi step: no barrier (same-wave DS ops are in-order)
#define VSTEP1(tt, CURP, E0, E1)                                              \
{                                                                             \
    const int cur_ = (CURP), nxt_ = 1 - cur_;                                 \
    const float e0_ = E0, e1_ = E1;                                           \
    E0 = logit[lbase + (size_t)CLAMPROW((tt) + 4) * TT + j0];                 \
    E1 = logit[lbase + (size_t)CLAMPROW((tt) + 4) * TT + j1];                 \
    float vA_; int iA_;                                                       \
    VCOL(vA_, iA_, tA, e0_, j0);                                              \
    float vB_; int iB_;                                                       \
    VCOL(vB_, iB_, tB, e1_, j1);                                              \
    stateLDS[nxt_ * TT + j0] = vA_;                                           \
    stateLDS[nxt_ * TT + j1] = vB_;                                           \
    hb[(size_t)(tt) * TT + j0] = (uint8_t)iA_;                                \
    hb[(size_t)(tt) * TT + j1] = (uint8_t)iB_;                                \
}

// ---- one forward column, within-lane ----
#define FCOL(OUTA, OUTP, TREG, ECOL)                                          \
{                                                                             \
    const f32x4* sp_ = (const f32x4*)(stateLDS + cur_ * TT);                  \
    f32x4 a0_ = {0.f, 0.f, 0.f, 0.f}, a1_ = {0.f, 0.f, 0.f, 0.f};             \
    _Pragma("unroll")                                                         \
    for (int cc = 0; cc < 16; ++cc) {                                         \
        a0_ = sp_[2 * cc] * TREG[2 * cc] + a0_;                               \
        a1_ = sp_[2 * cc + 1] * TREG[2 * cc + 1] + a1_;                       \
    }                                                                         \
    f32x4 s_ = a0_ + a1_;                                                     \
    float S_ = (s_.x + s_.y) + (s_.z + s_.w);                                 \
    OUTA = (ECOL) + Rcons_ + __logf(S_);                                      \
    OUTP = __expf(OUTA - Rpub_);                                              \
}

#define FSTEP1(tt, CURP, E0, E1)                                              \
{                                                                             \
    const int cur_ = (CURP), nxt_ = 1 - cur_;                                 \
    const float Rcons_ = ringLDS[((tt) - 3) & 3];                             \
    const float Rpub_  = ringLDS[((tt) - 2) & 3];                             \
    const float e0_ = E0, e1_ = E1;                                           \
    E0 = logit[lbase + (size_t)CLAMPROW((tt) + 4) * TT + j0];                 \
    E1 = logit[lbase + (size_t)CLAMPROW((tt) + 4) * TT + j1];                 \
    float pA_, pB_;                                                           \
    FCOL(alphaA, pA_, tEA, e0_);                                              \
    FCOL(alphaB, pB_, tEB, e1_);                                              \
    stateLDS[nxt_ * TT + j0] = pA_;                                           \
    stateLDS[nxt_ * TT + j1] = pB_;                                           \
    if (lane == 0) ringLDS[(tt) & 3] = alphaA;                                \
}

// ---------------- main kernel: 256 blocks x 64 threads (ONE WAVE per chain).
// role 0 (blocks 0..127) = viterbi, role 1 = forward + numerator.
// lane owns columns j0=lane, j1=lane+64. No barriers in the step loop. -------
__attribute__((amdgpu_flat_work_group_size(64, 64)))
__attribute__((amdgpu_waves_per_eu(1, 1)))
__global__ void crf_main1(const float* __restrict__ logit,
                          const int* __restrict__ seq_lens,
                          const float* __restrict__ trans,
                          const float* __restrict__ startT,
                          const float* __restrict__ endT,
                          const int* __restrict__ target,
                          uint8_t* __restrict__ histG,
                          float* __restrict__ scr_logZ,
                          int* __restrict__ scr_last,
                          float* __restrict__ scr_num)
{
    extern __shared__ float smem[];
    float* transLDS = smem;                     // 16512 floats
    float* stateLDS = smem + 16512;             // 2 * 128
    float* ringLDS  = smem + 16512 + 256;       // 4

    const int bid  = blockIdx.x;
    const int role = bid >> 7;
    const int b    = bid & (BB - 1);
    const int lane = threadIdx.x;
    const int j0   = lane;
    const int j1   = lane + 64;
    const int L = seq_lens[b];
    const size_t lbase = (size_t)b * (SS * TT);

    // stage transitions into padded LDS (same wave: DS in-order, barrier optional)
    for (int m = lane; m < TT * TT; m += 64)
        transLDS[(m >> 7) * TRP + (m & 127)] = trans[m];
    __syncthreads();

    // 4-deep rotating e-prefetch for both columns (rows 1..4, clamped)
    float e_a0 = logit[lbase + (size_t)CLAMPROW(1) * TT + j0];
    float e_a1 = logit[lbase + (size_t)CLAMPROW(1) * TT + j1];
    float e_b0 = logit[lbase + (size_t)CLAMPROW(2) * TT + j0];
    float e_b1 = logit[lbase + (size_t)CLAMPROW(2) * TT + j1];
    float e_c0 = logit[lbase + (size_t)CLAMPROW(3) * TT + j0];
    float e_c1 = logit[lbase + (size_t)CLAMPROW(3) * TT + j1];
    float e_d0 = logit[lbase + (size_t)CLAMPROW(4) * TT + j0];
    float e_d1 = logit[lbase + (size_t)CLAMPROW(4) * TT + j1];

    const float a0j0 = startT[j0] + logit[lbase + j0];
    const float a0j1 = startT[j1] + logit[lbase + j1];

    if (role == 0) {
        // =================== VITERBI (1 wave) ===================
        f32x4 tA[32], tB[32];   // trans columns j0, j1 — pinned in VGPRs
#pragma unroll
        for (int c = 0; c < 32; ++c) {
            tA[c].x = transLDS[(c * 4 + 0) * TRP + j0];
            tA[c].y = transLDS[(c * 4 + 1) * TRP + j0];
            tA[c].z = transLDS[(c * 4 + 2) * TRP + j0];
            tA[c].w = transLDS[(c * 4 + 3) * TRP + j0];
            PIN(tA[c]);
            tB[c].x = transLDS[(c * 4 + 0) * TRP + j1];
            tB[c].y = transLDS[(c * 4 + 1) * TRP + j1];
            tB[c].z = transLDS[(c * 4 + 2) * TRP + j1];
            tB[c].w = transLDS[(c * 4 + 3) * TRP + j1];
            PIN(tB[c]);
        }
        stateLDS[j0] = a0j0;
        stateLDS[j1] = a0j1;

        uint8_t* hb = histG + (size_t)b * (SS * TT);

        int t = 1;
        for (; t + 3 < L; t += 4) {
            VSTEP1(t + 0, 0, e_a0, e_a1);
            VSTEP1(t + 1, 1, e_b0, e_b1);
            VSTEP1(t + 2, 0, e_c0, e_c1);
            VSTEP1(t + 3, 1, e_d0, e_d1);
        }
        for (; t < L; ++t) {
            VSTEP1(t, ((t - 1) & 1), e_a0, e_a1);
            e_a0 = e_b0; e_b0 = e_c0; e_c0 = e_d0;
            e_a1 = e_b1; e_b1 = e_c1; e_c1 = e_d1;
        }

        // ---- last_tag = argmax_j(score + end), first-index (in-wave) ----
        const int fin = (L - 1) & 1;
        {
            float v0 = stateLDS[fin * TT + j0] + endT[j0];
            float v1 = stateLDS[fin * TT + j1] + endT[j1];
            float lv; int li;
            if (v1 > v0) { lv = v1; li = j1; } else { lv = v0; li = j0; }
#pragma unroll
            for (int off = 1; off < 64; off <<= 1) {
                float ov = __shfl_xor(lv, off);
                int oi = __shfl_xor(li, off);
                if (ov > lv || (ov == lv && oi < li)) { lv = ov; li = oi; }
            }
            if (lane == 0) scr_last[b] = li;
        }
        // ---- identity fill of hist rows [L, SS) ----
        const int colq = (lane & 7) * 16;
        const uint32_t w0 = 0x03020100u + 0x01010101u * (uint32_t)colq;
        const uint4 pat = make_uint4(w0, w0 + 0x04040404u, w0 + 0x08080808u, w0 + 0x0C0C0C0Cu);
        for (int t0 = L; t0 < SS; t0 += 8) {
            int tt = t0 + (lane >> 3);
            if (tt < SS) *(uint4*)(hb + (size_t)tt * TT + colq) = pat;
        }
    } else {
        // =================== FORWARD (1 wave) ===================
        f32x4 tEA[32], tEB[32];  // exp(trans) columns, pinned
#pragma unroll
        for (int c = 0; c < 32; ++c) {
            tEA[c].x = __expf(transLDS[(c * 4 + 0) * TRP + j0]);
            tEA[c].y = __expf(transLDS[(c * 4 + 1) * TRP + j0]);
            tEA[c].z = __expf(transLDS[(c * 4 + 2) * TRP + j0]);
            tEA[c].w = __expf(transLDS[(c * 4 + 3) * TRP + j0]);
            PIN(tEA[c]);
            tEB[c].x = __expf(transLDS[(c * 4 + 0) * TRP + j1]);
            tEB[c].y = __expf(transLDS[(c * 4 + 1) * TRP + j1]);
            tEB[c].z = __expf(transLDS[(c * 4 + 2) * TRP + j1]);
            tEB[c].w = __expf(transLDS[(c * 4 + 3) * TRP + j1]);
            PIN(tEB[c]);
        }
        const float R0 = startT[0] + logit[lbase + 0];  // alpha0[0], uniform
        float alphaA = a0j0, alphaB = a0j1;
        stateLDS[j0] = __expf(a0j0 - R0);
        stateLDS[j1] = __expf(a0j1 - R0);
        if (lane < 4) ringLDS[lane] = R0;

        int t = 1;
        for (; t + 3 < L; t += 4) {
            FSTEP1(t + 0, 0, e_a0, e_a1);
            FSTEP1(t + 1, 1, e_b0, e_b1);
            FSTEP1(t + 2, 0, e_c0, e_c1);
            FSTEP1(t + 3, 1, e_d0, e_d1);
        }
        for (; t < L; ++t) {
            FSTEP1(t, ((t - 1) & 1), e_a0, e_a1);
            e_a0 = e_b0; e_b0 = e_c0; e_c0 = e_d0;
            e_a1 = e_b1; e_b1 = e_c1; e_c1 = e_d1;
        }

        // ---- logZ epilogue (exact max, in-wave) ----
        const float f0 = alphaA + endT[j0];
        const float f1 = alphaB + endT[j1];
        float gm = fmaxf(f0, f1);
#pragma unroll
        for (int off = 1; off < 64; off <<= 1) gm = fmaxf(gm, __shfl_xor(gm, off));
        float se = __expf(f0 - gm) + __expf(f1 - gm);
#pragma unroll
        for (int off = 1; off < 64; off <<= 1) se += __shfl_xor(se, off);
        if (lane == 0) scr_logZ[b] = gm + __logf(se);

        // ---- numerator (gold path score) ----
        float acc = 0.f;
        for (int tt = lane; tt < L; tt += 64) {
            int tg = target[b * SS + tt];
            acc += logit[((size_t)b * SS + tt) * TT + tg];
            if (tt >= 1) acc += trans[target[b * SS + tt - 1] * TT + tg];
        }
#pragma unroll
        for (int off = 1; off < 64; off <<= 1) acc += __shfl_xor(acc, off);
        if (lane == 0) {
            float tot = acc + startT[target[b * SS]] + endT[target[b * SS + L - 1]];
            scr_num[b] = tot;
        }
    }
}

// ---------------- phase 2: per-segment parallel backtrace of all 128 end-tags ----------------
__global__ void crf_btseg(uint8_t* __restrict__ histG)
{
    const int c = blockIdx.x;    // segment 0..31
    const int b = blockIdx.y;    // batch
    const int tid = threadIdx.x; // 128
    __shared__ __align__(16) uint8_t hl[SEGK * TT];

    const int lo = (c == 0) ? 1 : c * SEGK;
    const int nr = (c == 0) ? 63 : 64;
    const uint8_t* src = histG + (size_t)b * (SS * TT) + (size_t)lo * TT;
    for (int k = tid; k < (nr * TT) / 16; k += 128)
        ((uint4*)hl)[k] = ((const uint4*)src)[k];
    __syncthreads();

    int tau = tid;
    uint32_t w[16];
#pragma unroll
    for (int q = 0; q < 16; ++q) w[q] = 0u;
    if (c == 0) {
#pragma unroll
        for (int r = 62; r >= 0; --r) {
            tau = hl[r * TT + tau];
            w[r >> 2] |= ((uint32_t)tau) << ((r & 3) * 8);
        }
    } else {
#pragma unroll
        for (int r = 63; r >= 0; --r) {
            tau = hl[r * TT + tau];
            w[r >> 2] |= ((uint32_t)tau) << ((r & 3) * 8);
        }
    }
    uint4* dst = (uint4*)(histG + (size_t)b * (SS * TT) + (size_t)c * 8192 + (size_t)tid * 64);
    dst[0] = make_uint4(w[0], w[1], w[2], w[3]);
    dst[1] = make_uint4(w[4], w[5], w[6], w[7]);
    dst[2] = make_uint4(w[8], w[9], w[10], w[11]);
    dst[3] = make_uint4(w[12], w[13], w[14], w[15]);
}

// ---------------- phase 3: serial chain over 32 segment maps per batch ----------------
__global__ void crf_btchain(const uint8_t* __restrict__ histG,
                            const int* __restrict__ scr_last,
                            int* __restrict__ scr_bt,
                            float* __restrict__ out_pred)
{
    const int b = threadIdx.x;
    if (b >= BB) return;
    int tau = scr_last[b];
    out_pred[(size_t)b * SS + (SS - 1)] = (float)tau;
    for (int c = NSEG - 1; c >= 0; --c) {
        scr_bt[b * NSEG + c] = tau;
        tau = histG[(size_t)b * (SS * TT) + (size_t)c * 8192 + (size_t)tau * 64];
    }
}

// ---------------- phase 4: parallel fill of pred from chosen paths ----------------
__global__ void crf_btfill(const uint8_t* __restrict__ histG,
                           const int* __restrict__ scr_bt,
                           float* __restrict__ out_pred)
{
    const int c = blockIdx.x;
    const int b = blockIdx.y;
    const int s = threadIdx.x;   // 64
    if (c == 0 && s > 62) return;
    const int js = scr_bt[b * NSEG + c];
    uint8_t v = histG[(size_t)b * (SS * TT) + (size_t)c * 8192 + (size_t)js * 64 + s];
    const int pos = (c == 0) ? s : (c * SEGK - 1 + s);
    out_pred[(size_t)b * SS + pos] = (float)v;
}

// ---------------- loss = mean(logZ - num) ----------------
__global__ void crf_loss(const float* __restrict__ scr_logZ, const float* __restrict__ scr_num,
                         float* __restrict__ out)
{
    const int tid = threadIdx.x; // 128
    __shared__ float p2[2];
    float v = (tid < BB) ? (scr_logZ[tid] - scr_num[tid]) : 0.0f;
#pragma unroll
    for (int off = 1; off < 64; off <<= 1) v += __shfl_xor(v, off);
    if ((tid & 63) == 0) p2[tid >> 6] = v;
    __syncthreads();
    if (tid == 0) out[0] = (p2[0] + p2[1]) / (float)BB;
}

// ---------------- log_probs: swap + log_softmax, one wave per row ----------------
__global__ void crf_logprobs(const float* __restrict__ logit,
                             const float* __restrict__ predF,
                             float* __restrict__ outLP)
{
    const int wid = threadIdx.x >> 6;
    const int lane = threadIdx.x & 63;
    const size_t row = (size_t)blockIdx.x * 4 + wid;
    const float2* rp = (const float2*)(logit + row * TT);
    float2 v = rp[lane];
    const int pred = (int)predF[row];

    float mv; int mi;
    if (v.y > v.x) { mv = v.y; mi = lane * 2 + 1; }
    else           { mv = v.x; mi = lane * 2; }
#pragma unroll
    for (int off = 1; off < 64; off <<= 1) {
        float ov = __shfl_xor(mv, off);
        int oi = __shfl_xor(mi, off);
        if (ov > mv || (ov == mv && oi < mi)) { mv = ov; mi = oi; }
    }
    float se = __expf(v.x - mv) + __expf(v.y - mv);
#pragma unroll
    for (int off = 1; off < 64; off <<= 1) se += __shfl_xor(se, off);
    const float lse = __logf(se);

    float px = __shfl(v.x, pred >> 1);
    float py = __shfl(v.y, pred >> 1);
    float vp = (pred & 1) ? py : px;

    float ox = (lane * 2 == pred) ? mv : ((lane * 2 == mi) ? vp : v.x);
    float oy = (lane * 2 + 1 == pred) ? mv : ((lane * 2 + 1 == mi) ? vp : v.y);
    float* op = outLP + row * TT + lane * 2;
    op[0] = (ox - mv) - lse;
    op[1] = (oy - mv) - lse;
}

extern "C" void kernel_launch(void* const* d_in, const int* in_sizes, int n_in,
                              void* d_out, int out_size, void* d_ws, size_t ws_size,
                              hipStream_t stream)
{
    const float* logit    = (const float*)d_in[0];
    const int*   target   = (const int*)d_in[1];
    const int*   seq_lens = (const int*)d_in[2];
    const float* trans    = (const float*)d_in[3];
    const float* startT   = (const float*)d_in[4];
    const float* endT     = (const float*)d_in[5];

    float* out      = (float*)d_out;
    float* out_pred = out + 1;
    float* outLP    = out + 1 + (size_t)BB * SS;                 // 262145
    uint8_t* histG  = (uint8_t*)(out + 262148);                  // 16B-aligned, 33.5MB
    float* scr      = out + ((size_t)1 + (size_t)BB * SS + (size_t)BB * SS * TT - 4480);
    float* scr_logZ = scr;                // 128
    float* scr_num  = scr + 128;          // 128
    int*   scr_last = (int*)(scr + 256);  // 128
    int*   scr_bt   = (int*)(scr + 384);  // 128*32

    const int dynLDS = (16512 + 256 + 8) * 4;  // ~67.1KB
    hipFuncSetAttribute((const void*)crf_main1,
                        hipFuncAttributeMaxDynamicSharedMemorySize, dynLDS);

    crf_main1<<<2 * BB, 64, dynLDS, stream>>>(logit, seq_lens, trans, startT, endT,
                                              target, histG, scr_logZ, scr_last, scr_num);
    crf_btseg<<<dim3(NSEG, BB), 128, 0, stream>>>(histG);
    crf_btchain<<<1, 128, 0, stream>>>(histG, scr_last, scr_bt, out_pred);
    crf_btfill<<<dim3(NSEG, BB), 64, 0, stream>>>(histG, scr_bt, out_pred);
    crf_loss<<<1, 128, 0, stream>>>(scr_logZ, scr_num, out);
    crf_logprobs<<<(BB * SS) / 4, 256, 0, stream>>>(logit, out_pred, outLP);
}

// Round 11
// 1460.239 us; speedup vs baseline: 6.8257x; 6.8257x over previous
//
#include <hip/hip_runtime.h>
#include <stdint.h>

#define BB 128
#define SS 2048
#define TT 128
#define NSEG 32
#define SEGK 64

// padded layouts (bank-conflict-free, validated R4-R9)
#define TRP 129              // trans row stride (129 % 32 == 1)
#define VSTRIDE 136          // state buffer stride
#define H1OFF 68             // half-1 offset (68 % 32 == 4 -> disjoint banks vs half-0)

typedef float f32x4 __attribute__((ext_vector_type(4)));

// raw barrier: drain LDS ops only (NOT vmcnt -> prefetch loads stay in flight)
#define BAR() asm volatile("s_waitcnt lgkmcnt(0)\n\ts_barrier" ::: "memory")
#define PIN(x) asm volatile("" : "+v"(x))

__device__ __forceinline__ float dpp_swap1_f(float x) {
    int i = __float_as_int(x);
    i = __builtin_amdgcn_update_dpp(0, i, 0xB1, 0xF, 0xF, true);
    return __int_as_float(i);
}
__device__ __forceinline__ int dpp_swap1_i(int x) {
    return __builtin_amdgcn_update_dpp(0, x, 0xB1, 0xF, 0xF, true);
}

#define CLAMPROW(k) (((k) < L) ? (k) : (L - 1))

// one viterbi step (R6-validated); EREG consumed (row tt), refilled row tt+8
#define VSTEP(tt, CURP, EREG)                                                 \
{                                                                             \
    const int cur_ = (CURP), nxt_ = 1 - cur_;                                 \
    const float e_ = EREG;                                                    \
    EREG = logit[lbase + (size_t)CLAMPROW((tt) + 8) * TT + j];                \
    const f32x4* sq_ = (const f32x4*)(vecLDS + cur_ * VSTRIDE + h * H1OFF);   \
    float cm_[8];                                                             \
    _Pragma("unroll")                                                         \
    for (int c = 0; c < 8; ++c) {                                             \
        f32x4 pa = sq_[2 * c] + tC[2 * c];                                    \
        f32x4 pb = sq_[2 * c + 1] + tC[2 * c + 1];                            \
        float m01 = fmaxf(pa.x, pa.y), m23 = fmaxf(pa.z, pa.w);               \
        float m45 = fmaxf(pb.x, pb.y), m67 = fmaxf(pb.z, pb.w);               \
        cm_[c] = fmaxf(fmaxf(m01, m23), fmaxf(m45, m67));                     \
    }                                                                         \
    float M_ = fmaxf(fmaxf(fmaxf(cm_[0], cm_[1]), fmaxf(cm_[2], cm_[3])),     \
                     fmaxf(fmaxf(cm_[4], cm_[5]), fmaxf(cm_[6], cm_[7])));    \
    const float Mall_ = fmaxf(M_, dpp_swap1_f(M_));                           \
    const float v_ = Mall_ + e_;   /* exact reference max value */            \
    int cwin_ = -1;                                                           \
    _Pragma("unroll")                                                         \
    for (int c = 7; c >= 0; --c) cwin_ = ((cm_[c] + e_) == v_) ? c : cwin_;   \
    int idx_ = 0x7fffffff;                                                    \
    if (cwin_ >= 0) {                                                         \
        const int basei_ = ibase0 + cwin_ * 8;                                \
        const float* tr_ = transLDS + (size_t)basei_ * TRP + j;               \
        const f32x4* sr_ = (const f32x4*)(vecLDS + cur_ * VSTRIDE + h * H1OFF + cwin_ * 8); \
        f32x4 ra_ = sr_[0], rb_ = sr_[1];                                     \
        float q0 = (ra_.x + tr_[0 * TRP]) + e_;                               \
        float q1 = (ra_.y + tr_[1 * TRP]) + e_;                               \
        float q2 = (ra_.z + tr_[2 * TRP]) + e_;                               \
        float q3 = (ra_.w + tr_[3 * TRP]) + e_;                               \
        float q4 = (rb_.x + tr_[4 * TRP]) + e_;                               \
        float q5 = (rb_.y + tr_[5 * TRP]) + e_;                               \
        float q6 = (rb_.z + tr_[6 * TRP]) + e_;                               \
        float q7 = (rb_.w + tr_[7 * TRP]) + e_;                               \
        idx_ = (q7 == v_) ? basei_ + 7 : idx_;                                \
        idx_ = (q6 == v_) ? basei_ + 6 : idx_;                                \
        idx_ = (q5 == v_) ? basei_ + 5 : idx_;                                \
        idx_ = (q4 == v_) ? basei_ + 4 : idx_;                                \
        idx_ = (q3 == v_) ? basei_ + 3 : idx_;                                \
        idx_ = (q2 == v_) ? basei_ + 2 : idx_;                                \
        idx_ = (q1 == v_) ? basei_ + 1 : idx_;                                \
        idx_ = (q0 == v_) ? basei_ + 0 : idx_;                                \
    }                                                                         \
    const int oidx_ = dpp_swap1_i(idx_);                                      \
    idx_ = (oidx_ < idx_) ? oidx_ : idx_;  /* first-index across halves */    \
    if (h == 0) {                                                             \
        vecLDS[nxt_ * VSTRIDE + joff] = v_;                                   \
        hb[(size_t)(tt) * TT + j] = (uint8_t)idx_;                            \
    }                                                                         \
    BAR();                                                                    \
}

// one forward step (R6-validated); depth-8 prefetch
#define FSTEP(tt, CURP, EREG)                                                 \
{                                                                             \
    const int cur_ = (CURP), nxt_ = 1 - cur_;                                 \
    const float Rcons_ = ringLDS[((tt) - 3) & 3];                             \
    const float Rpub_  = ringLDS[((tt) - 2) & 3];                             \
    const float e_ = EREG;                                                    \
    EREG = logit[lbase + (size_t)CLAMPROW((tt) + 8) * TT + j];                \
    const f32x4* aq_ = (const f32x4*)(vecLDS + cur_ * VSTRIDE + h * H1OFF);   \
    f32x4 s4_ = {0.f, 0.f, 0.f, 0.f}, s4b_ = {0.f, 0.f, 0.f, 0.f};            \
    _Pragma("unroll")                                                         \
    for (int c = 0; c < 16; c += 2) {                                         \
        s4_  = aq_[c] * tE[c] + s4_;                                          \
        s4b_ = aq_[c + 1] * tE[c + 1] + s4b_;                                 \
    }                                                                         \
    f32x4 st_ = s4_ + s4b_;                                                   \
    float Ssum_ = (st_.x + st_.y) + (st_.z + st_.w);                          \
    Ssum_ += dpp_swap1_f(Ssum_);                                              \
    alpha = e_ + Rcons_ + __logf(Ssum_);                                      \
    const float p_ = __expf(alpha - Rpub_);                                   \
    if (h == 0) vecLDS[nxt_ * VSTRIDE + joff] = p_;                           \
    if (tid == 0) ringLDS[(tt) & 3] = alpha;                                  \
    BAR();                                                                    \
}

// ---------------- main kernel: 256 blocks. role 0 = viterbi, role 1 = forward+num.
// 256 threads: j=tid>>1, h=tid&1 owns i-half [64h,64h+64). ----------------
__attribute__((amdgpu_flat_work_group_size(256, 256)))
__attribute__((amdgpu_waves_per_eu(1, 1)))
__global__ void crf_mainX(const float* __restrict__ logit,
                          const int* __restrict__ seq_lens,
                          const float* __restrict__ trans,
                          const float* __restrict__ startT,
                          const float* __restrict__ endT,
                          const int* __restrict__ target,
                          uint8_t* __restrict__ histG,
                          float* __restrict__ scr_logZ,
                          int* __restrict__ scr_last,
                          float* __restrict__ scr_num)
{
    extern __shared__ float smem[];
    float* transLDS = smem;                         // 16512 floats
    float* vecLDS   = smem + 16512;                 // 2 * VSTRIDE = 272
    float* ringLDS  = smem + 16512 + 272;           // 4
    float* redLDS   = smem + 16512 + 276;           // 8
    int*   redILDS  = (int*)(smem + 16512 + 284);   // 4
    float* sumLDS   = smem + 16512 + 288;           // 4

    const int bid = blockIdx.x;
    const int role = bid >> 7;
    const int b = bid & (BB - 1);
    const int tid = threadIdx.x;
    const int j = tid >> 1;
    const int h = tid & 1;
    const int ibase0 = h << 6;
    const int joff = j + ((j >= 64) ? (H1OFF - 64) : 0);
    const int L = seq_lens[b];
    const size_t lbase = (size_t)b * (SS * TT);

    // stage transitions into padded LDS (stride TRP)
    for (int m = tid; m < TT * TT; m += 256)
        transLDS[(m >> 7) * TRP + (m & 127)] = trans[m];
    __syncthreads();

    // 8-deep rotating prefetch registers (rows 1..8, clamped)
    float e_a = logit[lbase + (size_t)CLAMPROW(1) * TT + j];
    float e_b = logit[lbase + (size_t)CLAMPROW(2) * TT + j];
    float e_c = logit[lbase + (size_t)CLAMPROW(3) * TT + j];
    float e_d = logit[lbase + (size_t)CLAMPROW(4) * TT + j];
    float e_e = logit[lbase + (size_t)CLAMPROW(5) * TT + j];
    float e_f = logit[lbase + (size_t)CLAMPROW(6) * TT + j];
    float e_g = logit[lbase + (size_t)CLAMPROW(7) * TT + j];
    float e_h = logit[lbase + (size_t)CLAMPROW(8) * TT + j];

    if (role == 0) {
        // =================== VITERBI ===================
        f32x4 tC[16];  // trans[i][j] for my i-half, pinned in VGPRs
#pragma unroll
        for (int c = 0; c < 16; ++c) {
            tC[c].x = transLDS[(ibase0 + c * 4 + 0) * TRP + j];
            tC[c].y = transLDS[(ibase0 + c * 4 + 1) * TRP + j];
            tC[c].z = transLDS[(ibase0 + c * 4 + 2) * TRP + j];
            tC[c].w = transLDS[(ibase0 + c * 4 + 3) * TRP + j];
            PIN(tC[c]);
        }
        const float a0 = startT[j] + logit[lbase + j];
        if (h == 0) vecLDS[joff] = a0;
        __syncthreads();

        uint8_t* hb = histG + (size_t)b * (SS * TT);

        // steady state: 8 steps/iteration, static parity (t starts at 1, step 8)
        int t = 1;
        for (; t + 7 < L; t += 8) {
            VSTEP(t + 0, 0, e_a);
            VSTEP(t + 1, 1, e_b);
            VSTEP(t + 2, 0, e_c);
            VSTEP(t + 3, 1, e_d);
            VSTEP(t + 4, 0, e_e);
            VSTEP(t + 5, 1, e_f);
            VSTEP(t + 6, 0, e_g);
            VSTEP(t + 7, 1, e_h);
        }
        // tail (<=7 steps), dynamic parity, rotate registers
        for (; t < L; ++t) {
            VSTEP(t, ((t - 1) & 1), e_a);
            e_a = e_b; e_b = e_c; e_c = e_d; e_d = e_e;
            e_e = e_f; e_f = e_g; e_g = e_h;
        }

        // ---- last_tag = argmax_j(score + end), first-index ----
        const int fin = (L - 1) & 1;
        if (tid < 128) {
            const int toff = tid + ((tid >= 64) ? (H1OFF - 64) : 0);
            float lv = vecLDS[fin * VSTRIDE + toff] + endT[tid];
            int li = tid;
#pragma unroll
            for (int off = 1; off < 64; off <<= 1) {
                float ov = __shfl_xor(lv, off);
                int oi = __shfl_xor(li, off);
                if (ov > lv || (ov == lv && oi < li)) { lv = ov; li = oi; }
            }
            if ((tid & 63) == 0) { redLDS[tid >> 6] = lv; redILDS[tid >> 6] = li; }
        }
        __syncthreads();
        if (tid == 0) {
            int lt = (redLDS[1] > redLDS[0] ||
                      (redLDS[1] == redLDS[0] && redILDS[1] < redILDS[0]))
                     ? redILDS[1] : redILDS[0];
            scr_last[b] = lt;
        }
        // ---- identity fill of hist rows [L, SS) ----
        const int colq = (tid & 7) * 16;
        const uint32_t w0 = 0x03020100u + 0x01010101u * (uint32_t)colq;
        const uint4 pat = make_uint4(w0, w0 + 0x04040404u, w0 + 0x08080808u, w0 + 0x0C0C0C0Cu);
        for (int t0 = L; t0 < SS; t0 += 32) {
            int tt = t0 + (tid >> 3);
            if (tt < SS) *(uint4*)(hb + (size_t)tt * TT + colq) = pat;
        }
    } else {
        // =================== FORWARD (logZ) ===================
        f32x4 tE[16];  // exp(trans[i][j]), pinned
#pragma unroll
        for (int c = 0; c < 16; ++c) {
            tE[c].x = __expf(transLDS[(ibase0 + c * 4 + 0) * TRP + j]);
            tE[c].y = __expf(transLDS[(ibase0 + c * 4 + 1) * TRP + j]);
            tE[c].z = __expf(transLDS[(ibase0 + c * 4 + 2) * TRP + j]);
            tE[c].w = __expf(transLDS[(ibase0 + c * 4 + 3) * TRP + j]);
            PIN(tE[c]);
        }
        const float a0 = startT[j] + logit[lbase + j];
        const float R0 = startT[0] + logit[lbase + 0];  // alpha0[0], uniform
        float alpha = a0;
        if (h == 0) vecLDS[joff] = __expf(a0 - R0);
        if (tid < 4) ringLDS[tid] = R0;
        __syncthreads();

        int t = 1;
        for (; t + 7 < L; t += 8) {
            FSTEP(t + 0, 0, e_a);
            FSTEP(t + 1, 1, e_b);
            FSTEP(t + 2, 0, e_c);
            FSTEP(t + 3, 1, e_d);
            FSTEP(t + 4, 0, e_e);
            FSTEP(t + 5, 1, e_f);
            FSTEP(t + 6, 0, e_g);
            FSTEP(t + 7, 1, e_h);
        }
        for (; t < L; ++t) {
            FSTEP(t, ((t - 1) & 1), e_a);
            e_a = e_b; e_b = e_c; e_c = e_d; e_d = e_e;
            e_e = e_f; e_f = e_g; e_g = e_h;
        }

        // ---- logZ epilogue (exact max) ----
        const float fval = alpha + endT[j];
        float tmx = fval;
#pragma unroll
        for (int off = 1; off < 64; off <<= 1) tmx = fmaxf(tmx, __shfl_xor(tmx, off));
        if ((tid & 63) == 0) redLDS[4 + (tid >> 6)] = tmx;
        __syncthreads();
        const float gm = fmaxf(fmaxf(redLDS[4], redLDS[5]), fmaxf(redLDS[6], redLDS[7]));
        float se = (h == 0) ? __expf(fval - gm) : 0.f;
#pragma unroll
        for (int off = 1; off < 64; off <<= 1) se += __shfl_xor(se, off);
        if ((tid & 63) == 0) sumLDS[tid >> 6] = se;
        __syncthreads();
        if (tid == 0)
            scr_logZ[b] = gm + __logf(sumLDS[0] + sumLDS[1] + sumLDS[2] + sumLDS[3]);
        __syncthreads();

        // ---- numerator (gold path score) ----
        float acc = 0.f;
        for (int tt = tid; tt < L; tt += 256) {
            int tg = target[b * SS + tt];
            acc += logit[((size_t)b * SS + tt) * TT + tg];
            if (tt >= 1) acc += trans[target[b * SS + tt - 1] * TT + tg];
        }
#pragma unroll
        for (int off = 1; off < 64; off <<= 1) acc += __shfl_xor(acc, off);
        if ((tid & 63) == 0) sumLDS[tid >> 6] = acc;
        __syncthreads();
        if (tid == 0) {
            float tot = sumLDS[0] + sumLDS[1] + sumLDS[2] + sumLDS[3];
            tot += startT[target[b * SS]] + endT[target[b * SS + L - 1]];
            scr_num[b] = tot;
        }
    }
}

// ---------------- phase 2: per-segment parallel backtrace of all 128 end-tags ----------------
__global__ void crf_btseg(uint8_t* __restrict__ histG)
{
    const int c = blockIdx.x;    // segment 0..31
    const int b = blockIdx.y;    // batch
    const int tid = threadIdx.x; // 128
    __shared__ __align__(16) uint8_t hl[SEGK * TT];

    const int lo = (c == 0) ? 1 : c * SEGK;
    const int nr = (c == 0) ? 63 : 64;
    const uint8_t* src = histG + (size_t)b * (SS * TT) + (size_t)lo * TT;
    for (int k = tid; k < (nr * TT) / 16; k += 128)
        ((uint4*)hl)[k] = ((const uint4*)src)[k];
    __syncthreads();

    int tau = tid;
    uint32_t w[16];
#pragma unroll
    for (int q = 0; q < 16; ++q) w[q] = 0u;
    if (c == 0) {
#pragma unroll
        for (int r = 62; r >= 0; --r) {
            tau = hl[r * TT + tau];
            w[r >> 2] |= ((uint32_t)tau) << ((r & 3) * 8);
        }
    } else {
#pragma unroll
        for (int r = 63; r >= 0; --r) {
            tau = hl[r * TT + tau];
            w[r >> 2] |= ((uint32_t)tau) << ((r & 3) * 8);
        }
    }
    uint4* dst = (uint4*)(histG + (size_t)b * (SS * TT) + (size_t)c * 8192 + (size_t)tid * 64);
    dst[0] = make_uint4(w[0], w[1], w[2], w[3]);
    dst[1] = make_uint4(w[4], w[5], w[6], w[7]);
    dst[2] = make_uint4(w[8], w[9], w[10], w[11]);
    dst[3] = make_uint4(w[12], w[13], w[14], w[15]);
}

// ---------------- phase 3: serial chain over 32 segment maps per batch ----------------
__global__ void crf_btchain(const uint8_t* __restrict__ histG,
                            const int* __restrict__ scr_last,
                            int* __restrict__ scr_bt,
                            float* __restrict__ out_pred)
{
    const int b = threadIdx.x;
    if (b >= BB) return;
    int tau = scr_last[b];
    out_pred[(size_t)b * SS + (SS - 1)] = (float)tau;
    for (int c = NSEG - 1; c >= 0; --c) {
        scr_bt[b * NSEG + c] = tau;
        tau = histG[(size_t)b * (SS * TT) + (size_t)c * 8192 + (size_t)tau * 64];
    }
}

// ---------------- phase 4: parallel fill of pred from chosen paths ----------------
__global__ void crf_btfill(const uint8_t* __restrict__ histG,
                           const int* __restrict__ scr_bt,
                           float* __restrict__ out_pred)
{
    const int c = blockIdx.x;
    const int b = blockIdx.y;
    const int s = threadIdx.x;   // 64
    if (c == 0 && s > 62) return;
    const int js = scr_bt[b * NSEG + c];
    uint8_t v = histG[(size_t)b * (SS * TT) + (size_t)c * 8192 + (size_t)js * 64 + s];
    const int pos = (c == 0) ? s : (c * SEGK - 1 + s);
    out_pred[(size_t)b * SS + pos] = (float)v;
}

// ---------------- loss = mean(logZ - num) ----------------
__global__ void crf_loss(const float* __restrict__ scr_logZ, const float* __restrict__ scr_num,
                         float* __restrict__ out)
{
    const int tid = threadIdx.x; // 128
    __shared__ float p2[2];
    float v = (tid < BB) ? (scr_logZ[tid] - scr_num[tid]) : 0.0f;
#pragma unroll
    for (int off = 1; off < 64; off <<= 1) v += __shfl_xor(v, off);
    if ((tid & 63) == 0) p2[tid >> 6] = v;
    __syncthreads();
    if (tid == 0) out[0] = (p2[0] + p2[1]) / (float)BB;
}

// ---------------- log_probs: swap + log_softmax, one wave per row ----------------
__global__ void crf_logprobs(const float* __restrict__ logit,
                             const float* __restrict__ predF,
                             float* __restrict__ outLP)
{
    const int wid = threadIdx.x >> 6;
    const int lane = threadIdx.x & 63;
    const size_t row = (size_t)blockIdx.x * 4 + wid;
    const float2* rp = (const float2*)(logit + row * TT);
    float2 v = rp[lane];
    const int pred = (int)predF[row];

    float mv; int mi;
    if (v.y > v.x) { mv = v.y; mi = lane * 2 + 1; }
    else           { mv = v.x; mi = lane * 2; }
#pragma unroll
    for (int off = 1; off < 64; off <<= 1) {
        float ov = __shfl_xor(mv, off);
        int oi = __shfl_xor(mi, off);
        if (ov > mv || (ov == mv && oi < mi)) { mv = ov; mi = oi; }
    }
    float se = __expf(v.x - mv) + __expf(v.y - mv);
#pragma unroll
    for (int off = 1; off < 64; off <<= 1) se += __shfl_xor(se, off);
    const float lse = __logf(se);

    float px = __shfl(v.x, pred >> 1);
    float py = __shfl(v.y, pred >> 1);
    float vp = (pred & 1) ? py : px;

    float ox = (lane * 2 == pred) ? mv : ((lane * 2 == mi) ? vp : v.x);
    float oy = (lane * 2 + 1 == pred) ? mv : ((lane * 2 + 1 == mi) ? vp : v.y);
    float* op = outLP + row * TT + lane * 2;
    op[0] = (ox - mv) - lse;
    op[1] = (oy - mv) - lse;
}

extern "C" void kernel_launch(void* const* d_in, const int* in_sizes, int n_in,
                              void* d_out, int out_size, void* d_ws, size_t ws_size,
                              hipStream_t stream)
{
    const float* logit    = (const float*)d_in[0];
    const int*   target   = (const int*)d_in[1];
    const int*   seq_lens = (const int*)d_in[2];
    const float* trans    = (const float*)d_in[3];
    const float* startT   = (const float*)d_in[4];
    const float* endT     = (const float*)d_in[5];

    float* out      = (float*)d_out;
    float* out_pred = out + 1;
    float* outLP    = out + 1 + (size_t)BB * SS;                 // 262145
    uint8_t* histG  = (uint8_t*)(out + 262148);                  // 16B-aligned, 33.5MB
    float* scr      = out + ((size_t)1 + (size_t)BB * SS + (size_t)BB * SS * TT - 4480);
    float* scr_logZ = scr;                // 128
    float* scr_num  = scr + 128;          // 128
    int*   scr_last = (int*)(scr + 256);  // 128
    int*   scr_bt   = (int*)(scr + 384);  // 128*32

    const int dynLDS = (16512 + 292) * 4;  // ~67.2KB
    hipFuncSetAttribute((const void*)crf_mainX,
                        hipFuncAttributeMaxDynamicSharedMemorySize, dynLDS);

    crf_mainX<<<2 * BB, 256, dynLDS, stream>>>(logit, seq_lens, trans, startT, endT,
                                               target, histG, scr_logZ, scr_last, scr_num);
    crf_btseg<<<dim3(NSEG, BB), 128, 0, stream>>>(histG);
    crf_btchain<<<1, 128, 0, stream>>>(histG, scr_last, scr_bt, out_pred);
    crf_btfill<<<dim3(NSEG, BB), 64, 0, stream>>>(histG, scr_bt, out_pred);
    crf_loss<<<1, 128, 0, stream>>>(scr_logZ, scr_num, out);
    crf_logprobs<<<(BB * SS) / 4, 256, 0, stream>>>(logit, out_pred, outLP);
}